// Round 1
// baseline (469.227 us; speedup 1.0000x reference)
//
#include <hip/hip_runtime.h>
#include <hip/hip_bf16.h>

#define N_NODES 100000
#define IN_F 128
#define OUT_F 64

// ---------------------------------------------------------------------------
// Kernel 1: support = input @ W    [N_NODES, 128] x [128, 64] -> [N_NODES, 64]
// One block = 256 threads = 4 waves; each wave computes one output row.
// W staged in LDS (128*64*4 = 32 KB). Wlds[k*64+c] with c = lane -> bank-clean.
// ---------------------------------------------------------------------------
__global__ __launch_bounds__(256) void gemm_support_kernel(
    const float* __restrict__ in, const float* __restrict__ W,
    float* __restrict__ support)
{
    __shared__ float Wlds[IN_F * OUT_F];
    const float4* W4 = (const float4*)W;
    float4* Wl4 = (float4*)Wlds;
    // 8192 floats = 2048 float4; 256 threads -> 8 each
    #pragma unroll
    for (int i = 0; i < 8; ++i)
        Wl4[threadIdx.x + i * 256] = W4[threadIdx.x + i * 256];
    __syncthreads();

    const int r   = threadIdx.x >> 6;   // wave id 0..3
    const int c   = threadIdx.x & 63;   // feature
    const int row = blockIdx.x * 4 + r;
    if (row >= N_NODES) return;

    const float* __restrict__ inr = in + (long)row * IN_F;
    float acc = 0.f;
    #pragma unroll
    for (int k = 0; k < IN_F; ++k)
        acc = fmaf(inr[k], Wlds[k * OUT_F + c], acc);

    support[(long)row * OUT_F + c] = acc;
}

// ---------------------------------------------------------------------------
// Kernel 2: out[n][f] = bias[f]   (also serves as the zero-init of the
// accumulator; must run every call — harness poisons d_out once).
// ---------------------------------------------------------------------------
__global__ __launch_bounds__(256) void bias_init_kernel(
    float* __restrict__ out, const float* __restrict__ bias, int total4)
{
    const float4* b4 = (const float4*)bias;    // 16 float4
    float4* o4 = (float4*)out;
    int i = blockIdx.x * blockDim.x + threadIdx.x;
    int stride = gridDim.x * blockDim.x;
    for (; i < total4; i += stride)
        o4[i] = b4[i & 15];
}

// ---------------------------------------------------------------------------
// Kernel 3: COO scatter.  64 threads per edge (one per feature).
//   out[rows[e]*64 + f] += vals[e] * support[cols[e]*64 + f]
// support reads coalesced; atomics hit 64 consecutive floats per edge.
// ---------------------------------------------------------------------------
__global__ __launch_bounds__(256) void scatter_kernel(
    const float* __restrict__ vals, const int* __restrict__ rows,
    const int* __restrict__ cols, const float* __restrict__ support,
    float* __restrict__ out, int nE)
{
    const int e = blockIdx.x * 4 + (threadIdx.x >> 6);
    if (e >= nE) return;
    const int f = threadIdx.x & 63;

    const float v = vals[e];
    const int   r = rows[e];
    const int   c = cols[e];

    const float m = v * support[(long)c * OUT_F + f];
    atomicAdd(&out[(long)r * OUT_F + f], m);
}

extern "C" void kernel_launch(void* const* d_in, const int* in_sizes, int n_in,
                              void* d_out, int out_size, void* d_ws, size_t ws_size,
                              hipStream_t stream) {
    const float* input   = (const float*)d_in[0];   // [100000,128]
    const float* weights = (const float*)d_in[1];   // [128,64]
    const float* bias    = (const float*)d_in[2];   // [64]
    const float* adj_vals= (const float*)d_in[3];   // [E]
    const int*   adj_rows= (const int*)d_in[4];     // [E]
    const int*   adj_cols= (const int*)d_in[5];     // [E]
    const int nE = in_sizes[3];

    float* out     = (float*)d_out;                 // [100000,64]
    float* support = (float*)d_ws;                  // 100000*64*4 = 25.6 MB

    // 1) support = input @ W
    {
        dim3 grid((N_NODES + 3) / 4);
        hipLaunchKernelGGL(gemm_support_kernel, grid, dim3(256), 0, stream,
                           input, weights, support);
    }
    // 2) out = bias (broadcast)
    {
        int total4 = N_NODES * OUT_F / 4;   // 1.6M float4
        int blocks = 2048;
        hipLaunchKernelGGL(bias_init_kernel, dim3(blocks), dim3(256), 0, stream,
                           out, bias, total4);
    }
    // 3) out[r] += v * support[c]
    {
        dim3 grid((nE + 3) / 4);
        hipLaunchKernelGGL(scatter_kernel, grid, dim3(256), 0, stream,
                           adj_vals, adj_rows, adj_cols, support, out, nE);
    }
}

// Round 2
// 318.489 us; speedup vs baseline: 1.4733x; 1.4733x over previous
//
#include <hip/hip_runtime.h>
#include <hip/hip_bf16.h>

#define N_NODES 100000
#define IN_F 128
#define OUT_F 64

// ===========================================================================
// Kernel 1: support = input @ W    [N,128] x [128,64] -> [N,64]
// Block = 256 thr = 4 waves, handles 64 rows. lane = row, wave w owns cols
// [16w,16w+16). A staged in LDS [64][129] (pad: read bank = (lane+k)%32,
// 2-way = free). W read at wave-uniform addresses (readfirstlane) -> s_load.
// ===========================================================================
__global__ __launch_bounds__(256) void gemm_kernel(
    const float* __restrict__ in, const float* __restrict__ W,
    float* __restrict__ support)
{
    __shared__ float Alds[64 * 129];
    const int t = threadIdx.x;
    const long row0 = (long)blockIdx.x * 64;

    // stage 64x128 floats (2048 float4), coalesced
    #pragma unroll
    for (int i = 0; i < 8; ++i) {
        int fi = t + i * 256;           // float4 index
        int r  = fi >> 5;               // 32 float4 per row
        int k4 = (fi & 31) << 2;
        float4 v = make_float4(0.f, 0.f, 0.f, 0.f);
        if (row0 + r < N_NODES)
            v = *(const float4*)(in + (row0 + r) * IN_F + k4);
        Alds[r * 129 + k4 + 0] = v.x;
        Alds[r * 129 + k4 + 1] = v.y;
        Alds[r * 129 + k4 + 2] = v.z;
        Alds[r * 129 + k4 + 3] = v.w;
    }
    __syncthreads();

    const int lane = t & 63;
    const int c0   = __builtin_amdgcn_readfirstlane((t >> 6) << 4);
    const float* __restrict__ Wp = W + c0;

    float acc[16];
    #pragma unroll
    for (int i = 0; i < 16; ++i) acc[i] = 0.f;

    const float* Ar = Alds + lane * 129;
    for (int k = 0; k < IN_F; ++k) {
        const float a = Ar[k];
        const float4 w0 = *(const float4*)(Wp + k * OUT_F + 0);
        const float4 w1 = *(const float4*)(Wp + k * OUT_F + 4);
        const float4 w2 = *(const float4*)(Wp + k * OUT_F + 8);
        const float4 w3 = *(const float4*)(Wp + k * OUT_F + 12);
        acc[0]  = fmaf(a, w0.x, acc[0]);  acc[1]  = fmaf(a, w0.y, acc[1]);
        acc[2]  = fmaf(a, w0.z, acc[2]);  acc[3]  = fmaf(a, w0.w, acc[3]);
        acc[4]  = fmaf(a, w1.x, acc[4]);  acc[5]  = fmaf(a, w1.y, acc[5]);
        acc[6]  = fmaf(a, w1.z, acc[6]);  acc[7]  = fmaf(a, w1.w, acc[7]);
        acc[8]  = fmaf(a, w2.x, acc[8]);  acc[9]  = fmaf(a, w2.y, acc[9]);
        acc[10] = fmaf(a, w2.z, acc[10]); acc[11] = fmaf(a, w2.w, acc[11]);
        acc[12] = fmaf(a, w3.x, acc[12]); acc[13] = fmaf(a, w3.y, acc[13]);
        acc[14] = fmaf(a, w3.z, acc[14]); acc[15] = fmaf(a, w3.w, acc[15]);
    }

    const long orow = row0 + lane;
    if (orow < N_NODES) {
        float* o = support + orow * OUT_F + c0;
        *(float4*)(o + 0)  = make_float4(acc[0],  acc[1],  acc[2],  acc[3]);
        *(float4*)(o + 4)  = make_float4(acc[4],  acc[5],  acc[6],  acc[7]);
        *(float4*)(o + 8)  = make_float4(acc[8],  acc[9],  acc[10], acc[11]);
        *(float4*)(o + 12) = make_float4(acc[12], acc[13], acc[14], acc[15]);
    }
}

// ===========================================================================
// CSR build: zero counts -> histogram -> exclusive scan (3 kernels) -> fill
// ===========================================================================
__global__ __launch_bounds__(256) void zero_kernel(int* __restrict__ p, int n)
{
    int i = blockIdx.x * 256 + threadIdx.x;
    if (i < n) p[i] = 0;
}

__global__ __launch_bounds__(256) void hist_kernel(
    const int* __restrict__ rows, int* __restrict__ cnt, int nE)
{
    int e = blockIdx.x * 256 + threadIdx.x;
    if (e < nE) atomicAdd(&cnt[rows[e]], 1);
}

// scan pass 1: per-block (1024 elems) exclusive scan; block totals out.
__global__ __launch_bounds__(256) void scan1_kernel(
    const int* __restrict__ cnt, int* __restrict__ row_start,
    int* __restrict__ blockSums, int n)
{
    __shared__ int lds[256];
    const int b = blockIdx.x, t = threadIdx.x;
    const int base = b * 1024 + t * 4;

    int4 v = make_int4(0, 0, 0, 0);
    if (base + 3 < n)        v = *(const int4*)(cnt + base);
    else {
        if (base + 0 < n) v.x = cnt[base + 0];
        if (base + 1 < n) v.y = cnt[base + 1];
        if (base + 2 < n) v.z = cnt[base + 2];
        if (base + 3 < n) v.w = cnt[base + 3];
    }
    const int s0 = v.x, s01 = v.x + v.y, s012 = s01 + v.z;
    const int tot = s012 + v.w;

    lds[t] = tot;
    __syncthreads();
    int sum = tot;
    #pragma unroll
    for (int off = 1; off < 256; off <<= 1) {
        int y = (t >= off) ? lds[t - off] : 0;
        __syncthreads();
        sum += y;
        lds[t] = sum;
        __syncthreads();
    }
    const int excl = sum - tot;
    if (t == 255) blockSums[b] = sum;

    if (base + 0 < n) row_start[base + 0] = excl;
    if (base + 1 < n) row_start[base + 1] = excl + s0;
    if (base + 2 < n) row_start[base + 2] = excl + s01;
    if (base + 3 < n) row_start[base + 3] = excl + s012;
}

// scan pass 2: single block scans <=256 block sums, in-place exclusive.
__global__ __launch_bounds__(256) void scan2_kernel(int* __restrict__ blockSums, int nb)
{
    __shared__ int lds[256];
    const int t = threadIdx.x;
    const int orig = (t < nb) ? blockSums[t] : 0;
    lds[t] = orig;
    __syncthreads();
    int sum = orig;
    #pragma unroll
    for (int off = 1; off < 256; off <<= 1) {
        int y = (t >= off) ? lds[t - off] : 0;
        __syncthreads();
        sum += y;
        lds[t] = sum;
        __syncthreads();
    }
    if (t < nb) blockSums[t] = sum - orig;  // exclusive
}

// scan pass 3: add block offsets; init cursor = row_start; set row_start[N]=E.
__global__ __launch_bounds__(256) void scan3_kernel(
    int* __restrict__ row_start, int* __restrict__ cursor,
    const int* __restrict__ blockSums, int n, int nE)
{
    int i = blockIdx.x * 256 + threadIdx.x;
    if (i < n) {
        int v = row_start[i] + blockSums[i >> 10];
        row_start[i] = v;
        cursor[i]    = v;
    }
    if (i == 0) row_start[n] = nE;
}

__global__ __launch_bounds__(256) void fill_kernel(
    const int* __restrict__ rows, const int* __restrict__ cols,
    const float* __restrict__ vals, int* __restrict__ cursor,
    int2* __restrict__ pairs, int nE)
{
    int e = blockIdx.x * 256 + threadIdx.x;
    if (e >= nE) return;
    const int r = rows[e];
    const int pos = atomicAdd(&cursor[r], 1);
    pairs[pos] = make_int2(cols[e], __float_as_int(vals[e]));
}

// ===========================================================================
// Kernel 3: CSR SpMM gather. One wave per row, lane = feature.
//   out[r][f] = bias[f] + sum_j val[j] * support[col[j]][f]
// support gathers are 256B coalesced per wave; out written once (no atomics).
// ===========================================================================
__global__ __launch_bounds__(256) void spmm_kernel(
    const int* __restrict__ row_start, const int2* __restrict__ pairs,
    const float* __restrict__ support, const float* __restrict__ bias,
    float* __restrict__ out)
{
    const int wid  = threadIdx.x >> 6;
    const int lane = threadIdx.x & 63;
    const int r    = blockIdx.x * 4 + wid;
    if (r >= N_NODES) return;

    const int s = row_start[r];
    const int e = row_start[r + 1];

    float acc = bias[lane];
    int j = s;
    for (; j + 1 < e; j += 2) {
        int2 p0 = pairs[j];
        int2 p1 = pairs[j + 1];
        acc = fmaf(__int_as_float(p0.y), support[(long)p0.x * OUT_F + lane], acc);
        acc = fmaf(__int_as_float(p1.y), support[(long)p1.x * OUT_F + lane], acc);
    }
    if (j < e) {
        int2 p = pairs[j];
        acc = fmaf(__int_as_float(p.y), support[(long)p.x * OUT_F + lane], acc);
    }
    out[(long)r * OUT_F + lane] = acc;
}

// ===========================================================================
// Fallback path (ws too small): bias-init + atomic scatter (round-1 kernels)
// ===========================================================================
__global__ __launch_bounds__(256) void bias_init_kernel(
    float* __restrict__ out, const float* __restrict__ bias, int total4)
{
    const float4* b4 = (const float4*)bias;
    float4* o4 = (float4*)out;
    int i = blockIdx.x * blockDim.x + threadIdx.x;
    int stride = gridDim.x * blockDim.x;
    for (; i < total4; i += stride)
        o4[i] = b4[i & 15];
}

__global__ __launch_bounds__(256) void scatter_kernel(
    const float* __restrict__ vals, const int* __restrict__ rows,
    const int* __restrict__ cols, const float* __restrict__ support,
    float* __restrict__ out, int nE)
{
    const int e = blockIdx.x * 4 + (threadIdx.x >> 6);
    if (e >= nE) return;
    const int f = threadIdx.x & 63;
    const float m = vals[e] * support[(long)cols[e] * OUT_F + f];
    atomicAdd(&out[(long)rows[e] * OUT_F + f], m);
}

// ===========================================================================
extern "C" void kernel_launch(void* const* d_in, const int* in_sizes, int n_in,
                              void* d_out, int out_size, void* d_ws, size_t ws_size,
                              hipStream_t stream) {
    const float* input    = (const float*)d_in[0];
    const float* weights  = (const float*)d_in[1];
    const float* bias     = (const float*)d_in[2];
    const float* adj_vals = (const float*)d_in[3];
    const int*   adj_rows = (const int*)d_in[4];
    const int*   adj_cols = (const int*)d_in[5];
    const int nE = in_sizes[3];

    float* out = (float*)d_out;

    // workspace layout (all offsets 256B-aligned)
    char* ws = (char*)d_ws;
    const size_t off_support = 0;
    const size_t off_rs      = 25600000;                       // (N+1) ints
    const size_t off_cursor  = off_rs + 400128;                // N ints
    const size_t off_bsums   = off_cursor + 400128;            // 256 ints
    const size_t off_pairs   = off_bsums + 1024;               // E int2
    const size_t required    = off_pairs + (size_t)nE * 8;

    float* support  = (float*)(ws + off_support);
    int*   row_start= (int*)  (ws + off_rs);
    int*   cursor   = (int*)  (ws + off_cursor);
    int*   bsums    = (int*)  (ws + off_bsums);
    int2*  pairs    = (int2*) (ws + off_pairs);

    // 1) support = input @ W
    hipLaunchKernelGGL(gemm_kernel, dim3((N_NODES + 63) / 64), dim3(256), 0,
                       stream, input, weights, support);

    if (ws_size >= required) {
        const int nb = (N_NODES + 1023) / 1024;   // 98 scan blocks
        // 2) cnt (cursor region) = 0
        hipLaunchKernelGGL(zero_kernel, dim3((N_NODES + 255) / 256), dim3(256),
                           0, stream, cursor, N_NODES);
        // 3) histogram of rows
        hipLaunchKernelGGL(hist_kernel, dim3((nE + 255) / 256), dim3(256),
                           0, stream, adj_rows, cursor, nE);
        // 4) exclusive scan -> row_start; cursor re-init
        hipLaunchKernelGGL(scan1_kernel, dim3(nb), dim3(256), 0, stream,
                           cursor, row_start, bsums, N_NODES);
        hipLaunchKernelGGL(scan2_kernel, dim3(1), dim3(256), 0, stream,
                           bsums, nb);
        hipLaunchKernelGGL(scan3_kernel, dim3((N_NODES + 255) / 256), dim3(256),
                           0, stream, row_start, cursor, bsums, N_NODES, nE);
        // 5) fill CSR pairs
        hipLaunchKernelGGL(fill_kernel, dim3((nE + 255) / 256), dim3(256),
                           0, stream, adj_rows, adj_cols, adj_vals, cursor,
                           pairs, nE);
        // 6) gather SpMM + bias
        hipLaunchKernelGGL(spmm_kernel, dim3((N_NODES + 3) / 4), dim3(256),
                           0, stream, row_start, pairs, support, bias, out);
    } else {
        // fallback: atomic scatter
        hipLaunchKernelGGL(bias_init_kernel, dim3(2048), dim3(256), 0, stream,
                           out, bias, N_NODES * OUT_F / 4);
        hipLaunchKernelGGL(scatter_kernel, dim3((nE + 3) / 4), dim3(256),
                           0, stream, adj_vals, adj_rows, adj_cols, support,
                           out, nE);
    }
}